// Round 2
// baseline (272.560 us; speedup 1.0000x reference)
//
#include <hip/hip_runtime.h>
#include <hip/hip_bf16.h>
#include <stdint.h>

// Problem constants
#define INPUT_D 784
#define HIDDEN  64
#define OUTC    10
#define NTEST   10000
#define WVEC    50890
#define NBATCH  64
#define O1      50176      // W1 end / B1 start
#define O2      50240      // W2 start
#define O3      50880      // B2 start
#define KPAD    832        // 784 padded to 13*64
#define MPAD    10112      // 10000 padded to 79*128
#define NCOLS   4096       // 64 batches * 64 hidden cols
#define KTILES  13
#define H2      136        // hlds row stride (bf16 elements; 272B = 17*16B so b128-aligned)

typedef __attribute__((ext_vector_type(8))) short  short8;
typedef __attribute__((ext_vector_type(4))) float  floatx4;

__device__ inline void async_copy16(const void* g, void* lds) {
  __builtin_amdgcn_global_load_lds(
      (const __attribute__((address_space(1))) void*)g,
      (__attribute__((address_space(3))) void*)lds, 16, 0, 0);
}

// ---------------- prep kernels ----------------

// images (10000x784 f32) -> bf16 padded (MPAD x KPAD), zero pad rows/cols
__global__ void cast_images(const float* __restrict__ img, __hip_bfloat16* __restrict__ out) {
  const int r = blockIdx.x;
  const float* src = img + (size_t)r * INPUT_D;
  __hip_bfloat16* dst = out + (size_t)r * KPAD;
  for (int c = threadIdx.x; c < KPAD; c += blockDim.x) {
    float v = (r < NTEST && c < INPUT_D) ? src[c] : 0.f;
    dst[c] = __float2bfloat16(v);
  }
}

// W1 stacked rows: Wall[b*64+h][c] = inp2[b*WVEC + h*784 + c], bf16, K zero-padded
__global__ void cast_w(const float* __restrict__ inp2, __hip_bfloat16* __restrict__ out) {
  const int r = blockIdx.x;            // 0..4095
  const int b = r >> 6, h = r & 63;
  const float* src = inp2 + (size_t)b * WVEC + h * INPUT_D;
  __hip_bfloat16* dst = out + (size_t)r * KPAD;
  for (int c = threadIdx.x; c < KPAD; c += blockDim.x)
    dst[c] = __float2bfloat16(c < INPUT_D ? src[c] : 0.f);
}

// loss1: sum of squared diffs (float4 vectorized), atomic per block into accums[0]
__global__ void loss1_kernel(const float* __restrict__ a, const float* __restrict__ b,
                             float* __restrict__ accum) {
  const int n4 = (NBATCH * WVEC) / 4;   // 814240
  const float4* A4 = (const float4*)a;
  const float4* B4 = (const float4*)b;
  float s = 0.f;
  for (int i = blockIdx.x * blockDim.x + threadIdx.x; i < n4; i += gridDim.x * blockDim.x) {
    float4 x = A4[i], y = B4[i];
    float d0 = x.x - y.x, d1 = x.y - y.y, d2 = x.z - y.z, d3 = x.w - y.w;
    s += d0 * d0 + d1 * d1 + d2 * d2 + d3 * d3;
  }
  for (int off = 32; off; off >>= 1) s += __shfl_down(s, off);
  __shared__ float r[4];
  if ((threadIdx.x & 63) == 0) r[threadIdx.x >> 6] = s;
  __syncthreads();
  if (threadIdx.x == 0) atomicAdd(accum, r[0] + r[1] + r[2] + r[3]);
}

// ---------------- fused GEMM + stage-2 ----------------
// grid (79, 32); block 256. Tile: 128 samples x 128 hcols (2 batches).
__global__ __launch_bounds__(256)
void gemm_fused(const __hip_bfloat16* __restrict__ A,    // MPAD x KPAD
                const __hip_bfloat16* __restrict__ Bm,   // NCOLS x KPAD
                const float* __restrict__ inp2,
                const int* __restrict__ tar2,            // int32! (harness casts int64->int32)
                float* __restrict__ accums) {
  __shared__ __align__(16) char smem[40032];
  __hip_bfloat16* Alds  = (__hip_bfloat16*)smem;            // [0,16384)
  __hip_bfloat16* Blds  = (__hip_bfloat16*)(smem + 16384);  // [16384,32768)
  // epilogue overlays (hlds overlaps staging; rest beyond 32768)
  __hip_bfloat16* hlds  = (__hip_bfloat16*)smem;            // 128*H2*2 = 34816
  __hip_bfloat16* w2lds = (__hip_bfloat16*)(smem + 34816);  // 2*16*64*2 = 4096 -> 38912
  float*          B2s   = (float*)(smem + 38912);           // 20 floats -> 38992
  int*            tars  = (int*)(smem + 38992);             // 256 ints  -> 40016
  float*          red   = (float*)(smem + 40016);           // 4 floats  -> 40032

  const int tid  = threadIdx.x;
  const int lane = tid & 63;
  const int wave = tid >> 6;
  const int wr   = (wave >> 1) * 64;    // wave row offset in tile
  const int wc   = (wave & 1) * 64;     // wave col offset in tile
  const int row0 = blockIdx.x * 128;
  const int col0 = blockIdx.y * 128;
  const int bbase = col0 >> 6;          // first batch of the 2 this block handles

  floatx4 acc[4][4];
#pragma unroll
  for (int i = 0; i < 4; ++i)
#pragma unroll
    for (int j = 0; j < 4; ++j) acc[i][j] = (floatx4){0.f, 0.f, 0.f, 0.f};

  const int lr = lane >> 3;        // row within 8-row chunk
  const int lc = (lane & 7) * 8;   // col offset within BK

  for (int kt = 0; kt < KTILES; ++kt) {
    const int k0 = kt * 64;
#pragma unroll
    for (int c = 0; c < 4; ++c) {
      const int ch = wave * 4 + c;   // 16 chunks of 8 rows each
      async_copy16(A  + (size_t)(row0 + ch * 8 + lr) * KPAD + k0 + lc, (char*)Alds + ch * 1024);
      async_copy16(Bm + (size_t)(col0 + ch * 8 + lr) * KPAD + k0 + lc, (char*)Blds + ch * 1024);
    }
    __syncthreads();
#pragma unroll
    for (int ks = 0; ks < 2; ++ks) {
      const int koff = ks * 32 + (lane >> 4) * 8;
      short8 a[4], b[4];
#pragma unroll
      for (int mi = 0; mi < 4; ++mi)
        a[mi] = *(const short8*)&Alds[(wr + mi * 16 + (lane & 15)) * 64 + koff];
#pragma unroll
      for (int ni = 0; ni < 4; ++ni)
        b[ni] = *(const short8*)&Blds[(wc + ni * 16 + (lane & 15)) * 64 + koff];
#pragma unroll
      for (int mi = 0; mi < 4; ++mi)
#pragma unroll
        for (int ni = 0; ni < 4; ++ni)
          acc[mi][ni] = __builtin_amdgcn_mfma_f32_16x16x32_bf16(a[mi], b[ni], acc[mi][ni], 0, 0, 0);
    }
    __syncthreads();
  }

  // ---- epilogue phase 1: load W2(bf16)/B2/targets into LDS; write h(bias+relu, bf16) ----
  for (int i = tid; i < 2048; i += 256) {
    const int bi = i >> 10, rem = i & 1023;
    const int o = rem >> 6, k = rem & 63;
    float v = (o < OUTC) ? inp2[(size_t)(bbase + bi) * WVEC + O2 + o * HIDDEN + k] : 0.f;
    w2lds[i] = __float2bfloat16(v);
  }
  if (tid < 20) B2s[tid] = inp2[(size_t)(bbase + tid / 10) * WVEC + O3 + tid % 10];
  {
    const int bi = tid >> 7, m = tid & 127;
    const int sample = row0 + m;
    tars[tid] = (sample < NTEST) ? tar2[(size_t)(bbase + bi) * NTEST + sample] : 0;
  }
#pragma unroll
  for (int ni = 0; ni < 4; ++ni) {
    const int n = wc + ni * 16 + (lane & 15);  // local col 0..127
    const float b1 = inp2[(size_t)(bbase + (n >> 6)) * WVEC + O1 + (n & 63)];
#pragma unroll
    for (int mi = 0; mi < 4; ++mi) {
      const int m = wr + mi * 16 + (lane >> 4) * 4;  // C layout: row=(lane>>4)*4+r, col=lane&15
#pragma unroll
      for (int r = 0; r < 4; ++r) {
        float v = acc[mi][ni][r] + b1;
        hlds[(size_t)(m + r) * H2 + n] = __float2bfloat16(v > 0.f ? v : 0.f);
      }
    }
  }
  __syncthreads();

  // ---- epilogue phase 2: logits via MFMA, log-softmax via 16-lane shuffles, CE ----
  const int col = lane & 15;
  const int q   = lane >> 4;
  float celocal = 0.f;
#pragma unroll
  for (int i = 0; i < 4; ++i) {
    const int task = wave * 4 + i;    // 16 tasks: 8 m-tiles x 2 batches
    const int mt = task & 7;
    const int bi = task >> 3;
    short8 af0 = *(const short8*)&hlds[(size_t)(mt * 16 + col) * H2 + bi * 64 + q * 8];
    short8 af1 = *(const short8*)&hlds[(size_t)(mt * 16 + col) * H2 + bi * 64 + 32 + q * 8];
    short8 bf0 = *(const short8*)&w2lds[(bi * 16 + col) * 64 + q * 8];
    short8 bf1 = *(const short8*)&w2lds[(bi * 16 + col) * 64 + 32 + q * 8];
    floatx4 lacc = (floatx4){0.f, 0.f, 0.f, 0.f};
    lacc = __builtin_amdgcn_mfma_f32_16x16x32_bf16(af0, bf0, lacc, 0, 0, 0);
    lacc = __builtin_amdgcn_mfma_f32_16x16x32_bf16(af1, bf1, lacc, 0, 0, 0);
    const float b2 = (col < OUTC) ? B2s[bi * OUTC + col] : 0.f;
#pragma unroll
    for (int r = 0; r < 4; ++r) {
      float lv = (col < OUTC) ? (lacc[r] + b2) : -1e30f;
      float mx = lv;
      mx = fmaxf(mx, __shfl_xor(mx, 1));
      mx = fmaxf(mx, __shfl_xor(mx, 2));
      mx = fmaxf(mx, __shfl_xor(mx, 4));
      mx = fmaxf(mx, __shfl_xor(mx, 8));
      float ex = __expf(lv - mx);
      float sm = ex;
      sm += __shfl_xor(sm, 1);
      sm += __shfl_xor(sm, 2);
      sm += __shfl_xor(sm, 4);
      sm += __shfl_xor(sm, 8);
      const float lse = mx + __logf(sm);
      const int row = mt * 16 + q * 4 + r;
      const int tar = tars[bi * 128 + row];
      if (col == tar && (row0 + row) < NTEST) celocal += (lse - lv);
    }
  }
  for (int off = 32; off; off >>= 1) celocal += __shfl_down(celocal, off);
  if (lane == 0) red[wave] = celocal;
  __syncthreads();
  if (tid == 0) atomicAdd(&accums[1], red[0] + red[1] + red[2] + red[3]);
}

// ---------------- finalize ----------------
__global__ void finalize(const float* __restrict__ accums, float* __restrict__ out) {
  const float l1 = 20.f * accums[0] / (float)(NBATCH * WVEC);
  const float l2 = accums[1] / (float)(NBATCH * NTEST);
  out[0] = l1 + l2;
  out[1] = l1;
  out[2] = l2;
}

// ---------------- fallback (ws too small): naive fp32, correctness only ----------------
__global__ void naive_ce(const float* __restrict__ inp2, const int* __restrict__ tar2,
                         const float* __restrict__ images, float* __restrict__ accum) {
  const int id = blockIdx.x * blockDim.x + threadIdx.x;  // 640000 threads
  float ce = 0.f;
  if (id < NBATCH * NTEST) {
    const int b = id / NTEST, n = id % NTEST;
    const float* w = inp2 + (size_t)b * WVEC;
    const float* im = images + (size_t)n * INPUT_D;
    float h[HIDDEN];
    for (int hh = 0; hh < HIDDEN; ++hh) {
      float s = w[O1 + hh];
      for (int d = 0; d < INPUT_D; ++d) s = fmaf(im[d], w[hh * INPUT_D + d], s);
      h[hh] = s > 0.f ? s : 0.f;
    }
    float mx = -1e30f, lg[OUTC];
    for (int o = 0; o < OUTC; ++o) {
      float s = w[O3 + o];
      for (int hh = 0; hh < HIDDEN; ++hh) s = fmaf(h[hh], w[O2 + o * HIDDEN + hh], s);
      lg[o] = s;
      mx = fmaxf(mx, s);
    }
    float sm = 0.f;
    for (int o = 0; o < OUTC; ++o) sm += __expf(lg[o] - mx);
    const float lse = mx + __logf(sm);
    const int t = tar2[(size_t)b * NTEST + n];
    float lt = lg[0];
    for (int o = 1; o < OUTC; ++o) lt = (o == t) ? lg[o] : lt;
    ce = lse - lt;
  }
  for (int off = 32; off; off >>= 1) ce += __shfl_down(ce, off);
  __shared__ float r[4];
  if ((threadIdx.x & 63) == 0) r[threadIdx.x >> 6] = ce;
  __syncthreads();
  if (threadIdx.x == 0) atomicAdd(accum, r[0] + r[1] + r[2] + r[3]);
}

extern "C" void kernel_launch(void* const* d_in, const int* in_sizes, int n_in,
                              void* d_out, int out_size, void* d_ws, size_t ws_size,
                              hipStream_t stream) {
  const float* inp1   = (const float*)d_in[0];
  const float* tar1   = (const float*)d_in[1];
  const float* inp2   = (const float*)d_in[2];
  const int*   tar2   = (const int*)d_in[3];   // int32 per harness convention
  const float* images = (const float*)d_in[4];
  float*       out    = (float*)d_out;

  const size_t img_bytes  = (size_t)MPAD * KPAD * sizeof(__hip_bfloat16);
  const size_t wall_bytes = (size_t)NCOLS * KPAD * sizeof(__hip_bfloat16);
  const size_t needed     = 256 + img_bytes + wall_bytes;

  if (ws_size >= needed) {
    float* accums = (float*)d_ws;
    __hip_bfloat16* imgb = (__hip_bfloat16*)((char*)d_ws + 256);
    __hip_bfloat16* wall = (__hip_bfloat16*)((char*)d_ws + 256 + img_bytes);
    hipMemsetAsync(d_ws, 0, 256, stream);
    loss1_kernel<<<1024, 256, 0, stream>>>(inp1, tar1, accums);
    cast_images<<<MPAD, 256, 0, stream>>>(images, imgb);
    cast_w<<<NCOLS, 256, 0, stream>>>(inp2, wall);
    gemm_fused<<<dim3(79, 32), 256, 0, stream>>>(imgb, wall, inp2, tar2, accums);
    finalize<<<1, 1, 0, stream>>>(accums, out);
  } else {
    // fallback: use d_out[1]/d_out[2] as raw accumulators
    hipMemsetAsync(d_out, 0, 3 * sizeof(float), stream);
    loss1_kernel<<<1024, 256, 0, stream>>>(inp1, tar1, out + 1);
    naive_ce<<<(NBATCH * NTEST + 255) / 256, 256, 0, stream>>>(inp2, tar2, images, out + 2);
    finalize<<<1, 1, 0, stream>>>(out + 1, out);
  }
}

// Round 3
// 238.287 us; speedup vs baseline: 1.1438x; 1.1438x over previous
//
#include <hip/hip_runtime.h>
#include <hip/hip_bf16.h>
#include <stdint.h>

// Problem constants
#define INPUT_D 784
#define HIDDEN  64
#define OUTC    10
#define NTEST   10000
#define WVEC    50890
#define NBATCH  64
#define O1      50176      // W1 end / B1 start
#define O2      50240      // W2 start
#define O3      50880      // B2 start
#define KPAD    832        // 784 padded to 13*64
#define MPAD    10240      // 10000 padded to 80*128 (80 %8==0 -> row-tile pins to one XCD)
#define MTILES  80
#define NCOLS   4096       // 64 batches * 64 hidden cols
#define KTILES  13
#define H2      136        // hlds row stride (bf16 elements; 272B = 17*16B so b128-aligned)

typedef __attribute__((ext_vector_type(8))) short  short8;
typedef __attribute__((ext_vector_type(4))) float  floatx4;

__device__ inline void async_copy16(const void* g, void* lds) {
  __builtin_amdgcn_global_load_lds(
      (const __attribute__((address_space(1))) void*)g,
      (__attribute__((address_space(3))) void*)lds, 16, 0, 0);
}

// ---------------- prep: cast images + W1 to bf16, K-padded, in one kernel ----------------
// blocks [0,MPAD): image rows;  [MPAD, MPAD+NCOLS): W1 rows (Wall[b*64+h][c])
__global__ void cast_prep(const float* __restrict__ img, const float* __restrict__ inp2,
                          __hip_bfloat16* __restrict__ outI, __hip_bfloat16* __restrict__ outW) {
  const int r = blockIdx.x;
  const int c = threadIdx.x * 4;
  if (c >= KPAD) return;
  const float* src;
  __hip_bfloat16* dst;
  bool valid;
  if (r < MPAD) {
    valid = (r < NTEST);
    src = img + (size_t)r * INPUT_D;
    dst = outI + (size_t)r * KPAD;
  } else {
    const int rr = r - MPAD;
    valid = true;
    src = inp2 + (size_t)(rr >> 6) * WVEC + (rr & 63) * INPUT_D;
    dst = outW + (size_t)rr * KPAD;
  }
  float4 v = make_float4(0.f, 0.f, 0.f, 0.f);
  if (valid && (c + 4) <= INPUT_D) v = *(const float4*)(src + c);   // 784%4==0
  __hip_bfloat16 tmp[4] = {__float2bfloat16(v.x), __float2bfloat16(v.y),
                           __float2bfloat16(v.z), __float2bfloat16(v.w)};
  *(ushort4*)(dst + c) = *(const ushort4*)tmp;
}

// loss1: sum of squared diffs (float4 vectorized), atomic per block into accums[0]
__global__ void loss1_kernel(const float* __restrict__ a, const float* __restrict__ b,
                             float* __restrict__ accum) {
  const int n4 = (NBATCH * WVEC) / 4;   // 814240
  const float4* A4 = (const float4*)a;
  const float4* B4 = (const float4*)b;
  float s = 0.f;
  for (int i = blockIdx.x * blockDim.x + threadIdx.x; i < n4; i += gridDim.x * blockDim.x) {
    float4 x = A4[i], y = B4[i];
    float d0 = x.x - y.x, d1 = x.y - y.y, d2 = x.z - y.z, d3 = x.w - y.w;
    s += d0 * d0 + d1 * d1 + d2 * d2 + d3 * d3;
  }
  for (int off = 32; off; off >>= 1) s += __shfl_down(s, off);
  __shared__ float r[4];
  if ((threadIdx.x & 63) == 0) r[threadIdx.x >> 6] = s;
  __syncthreads();
  if (threadIdx.x == 0) atomicAdd(accum, r[0] + r[1] + r[2] + r[3]);
}

// ---------------- fused GEMM + stage-2 ----------------
// grid (80, 32); block 256. Tile: 128 samples x 128 hcols (2 batches).
// LDS K-tiles are XOR-swizzled: slot (row r, phys p) holds global 16B-chunk p^(r&7),
// so quad reads spread over all 32 banks (2-way max, free) instead of 16-way.
__global__ __launch_bounds__(256)
void gemm_fused(const __hip_bfloat16* __restrict__ A,    // MPAD x KPAD
                const __hip_bfloat16* __restrict__ Bm,   // NCOLS x KPAD
                const float* __restrict__ inp2,
                const int* __restrict__ tar2,            // int32 (harness casts int64->int32)
                float* __restrict__ accums) {
  __shared__ __align__(16) char smem[40032];
  __hip_bfloat16* Alds  = (__hip_bfloat16*)smem;            // [0,16384)
  __hip_bfloat16* Blds  = (__hip_bfloat16*)(smem + 16384);  // [16384,32768)
  // epilogue overlays (hlds overlaps staging; rest beyond 32768)
  __hip_bfloat16* hlds  = (__hip_bfloat16*)smem;            // 128*H2*2 = 34816
  __hip_bfloat16* w2lds = (__hip_bfloat16*)(smem + 34816);  // 2*16*64*2 = 4096 -> 38912
  float*          B2s   = (float*)(smem + 38912);           // 20 floats -> 38992
  int*            tars  = (int*)(smem + 38992);             // 256 ints  -> 40016
  float*          red   = (float*)(smem + 40016);           // 4 floats  -> 40032

  const int tid  = threadIdx.x;
  const int lane = tid & 63;
  const int wave = tid >> 6;
  const int wr   = (wave >> 1) * 64;    // wave row offset in tile
  const int wc   = (wave & 1) * 64;     // wave col offset in tile
  const int row0 = blockIdx.x * 128;
  const int col0 = blockIdx.y * 128;
  const int bbase = col0 >> 6;          // first batch of the 2 this block handles

  floatx4 acc[4][4];
#pragma unroll
  for (int i = 0; i < 4; ++i)
#pragma unroll
    for (int j = 0; j < 4; ++j) acc[i][j] = (floatx4){0.f, 0.f, 0.f, 0.f};

  const int lr = lane >> 3;                        // row within 8-row chunk
  const int lc = (((lane & 7) ^ lr) * 8);          // swizzled source k-chunk
  const int sxor = lane & 7;                       // read-side swizzle (r&7 == lane&7)

  for (int kt = 0; kt < KTILES; ++kt) {
    const int k0 = kt * 64;
#pragma unroll
    for (int c = 0; c < 4; ++c) {
      const int ch = wave * 4 + c;   // 16 chunks of 8 rows each
      async_copy16(A  + (size_t)(row0 + ch * 8 + lr) * KPAD + k0 + lc, (char*)Alds + ch * 1024);
      async_copy16(Bm + (size_t)(col0 + ch * 8 + lr) * KPAD + k0 + lc, (char*)Blds + ch * 1024);
    }
    __syncthreads();
#pragma unroll
    for (int ks = 0; ks < 2; ++ks) {
      const int slog = ks * 4 + (lane >> 4);       // logical 16B chunk within row
      const int koff = (slog ^ sxor) * 8;          // swizzled element offset
      short8 a[4], b[4];
#pragma unroll
      for (int mi = 0; mi < 4; ++mi)
        a[mi] = *(const short8*)&Alds[(wr + mi * 16 + (lane & 15)) * 64 + koff];
#pragma unroll
      for (int ni = 0; ni < 4; ++ni)
        b[ni] = *(const short8*)&Blds[(wc + ni * 16 + (lane & 15)) * 64 + koff];
#pragma unroll
      for (int mi = 0; mi < 4; ++mi)
#pragma unroll
        for (int ni = 0; ni < 4; ++ni)
          acc[mi][ni] = __builtin_amdgcn_mfma_f32_16x16x32_bf16(a[mi], b[ni], acc[mi][ni], 0, 0, 0);
    }
    __syncthreads();
  }

  // ---- epilogue phase 1: load W2(bf16)/B2/targets into LDS; write h(bias+relu, bf16) ----
  for (int i = tid; i < 2048; i += 256) {
    const int bi = i >> 10, rem = i & 1023;
    const int o = rem >> 6, k = rem & 63;
    float v = (o < OUTC) ? inp2[(size_t)(bbase + bi) * WVEC + O2 + o * HIDDEN + k] : 0.f;
    w2lds[i] = __float2bfloat16(v);
  }
  if (tid < 20) B2s[tid] = inp2[(size_t)(bbase + tid / 10) * WVEC + O3 + tid % 10];
  {
    const int bi = tid >> 7, m = tid & 127;
    const int sample = row0 + m;
    tars[tid] = (sample < NTEST) ? tar2[(size_t)(bbase + bi) * NTEST + sample] : 0;
  }
#pragma unroll
  for (int ni = 0; ni < 4; ++ni) {
    const int n = wc + ni * 16 + (lane & 15);  // local col 0..127
    const float b1 = inp2[(size_t)(bbase + (n >> 6)) * WVEC + O1 + (n & 63)];
#pragma unroll
    for (int mi = 0; mi < 4; ++mi) {
      const int m = wr + mi * 16 + (lane >> 4) * 4;  // C layout: row=(lane>>4)*4+r, col=lane&15
#pragma unroll
      for (int r = 0; r < 4; ++r) {
        float v = acc[mi][ni][r] + b1;
        hlds[(size_t)(m + r) * H2 + n] = __float2bfloat16(v > 0.f ? v : 0.f);
      }
    }
  }
  __syncthreads();

  // ---- epilogue phase 2: logits via MFMA, log-softmax via 16-lane shuffles, CE ----
  const int col = lane & 15;
  const int q   = lane >> 4;
  float celocal = 0.f;
#pragma unroll
  for (int i = 0; i < 4; ++i) {
    const int task = wave * 4 + i;    // 16 tasks: 8 m-tiles x 2 batches
    const int mt = task & 7;
    const int bi = task >> 3;
    short8 af0 = *(const short8*)&hlds[(size_t)(mt * 16 + col) * H2 + bi * 64 + q * 8];
    short8 af1 = *(const short8*)&hlds[(size_t)(mt * 16 + col) * H2 + bi * 64 + 32 + q * 8];
    short8 bf0 = *(const short8*)&w2lds[(bi * 16 + col) * 64 + q * 8];
    short8 bf1 = *(const short8*)&w2lds[(bi * 16 + col) * 64 + 32 + q * 8];
    floatx4 lacc = (floatx4){0.f, 0.f, 0.f, 0.f};
    lacc = __builtin_amdgcn_mfma_f32_16x16x32_bf16(af0, bf0, lacc, 0, 0, 0);
    lacc = __builtin_amdgcn_mfma_f32_16x16x32_bf16(af1, bf1, lacc, 0, 0, 0);
    const float b2 = (col < OUTC) ? B2s[bi * OUTC + col] : 0.f;
#pragma unroll
    for (int r = 0; r < 4; ++r) {
      float lv = (col < OUTC) ? (lacc[r] + b2) : -1e30f;
      float mx = lv;
      mx = fmaxf(mx, __shfl_xor(mx, 1));
      mx = fmaxf(mx, __shfl_xor(mx, 2));
      mx = fmaxf(mx, __shfl_xor(mx, 4));
      mx = fmaxf(mx, __shfl_xor(mx, 8));
      float ex = __expf(lv - mx);
      float sm = ex;
      sm += __shfl_xor(sm, 1);
      sm += __shfl_xor(sm, 2);
      sm += __shfl_xor(sm, 4);
      sm += __shfl_xor(sm, 8);
      const float lse = mx + __logf(sm);
      const int row = mt * 16 + q * 4 + r;
      const int tar = tars[bi * 128 + row];
      if (col == tar && (row0 + row) < NTEST) celocal += (lse - lv);
    }
  }
  for (int off = 32; off; off >>= 1) celocal += __shfl_down(celocal, off);
  if (lane == 0) red[wave] = celocal;
  __syncthreads();
  if (tid == 0) atomicAdd(&accums[1], red[0] + red[1] + red[2] + red[3]);
}

// ---------------- finalize ----------------
__global__ void finalize(const float* __restrict__ accums, float* __restrict__ out) {
  const float l1 = 20.f * accums[0] / (float)(NBATCH * WVEC);
  const float l2 = accums[1] / (float)(NBATCH * NTEST);
  out[0] = l1 + l2;
  out[1] = l1;
  out[2] = l2;
}

// ---------------- fallback (ws too small): naive fp32, correctness only ----------------
__global__ void naive_ce(const float* __restrict__ inp2, const int* __restrict__ tar2,
                         const float* __restrict__ images, float* __restrict__ accum) {
  const int id = blockIdx.x * blockDim.x + threadIdx.x;  // 640000 threads
  float ce = 0.f;
  if (id < NBATCH * NTEST) {
    const int b = id / NTEST, n = id % NTEST;
    const float* w = inp2 + (size_t)b * WVEC;
    const float* im = images + (size_t)n * INPUT_D;
    float h[HIDDEN];
    for (int hh = 0; hh < HIDDEN; ++hh) {
      float s = w[O1 + hh];
      for (int d = 0; d < INPUT_D; ++d) s = fmaf(im[d], w[hh * INPUT_D + d], s);
      h[hh] = s > 0.f ? s : 0.f;
    }
    float mx = -1e30f, lg[OUTC];
    for (int o = 0; o < OUTC; ++o) {
      float s = w[O3 + o];
      for (int hh = 0; hh < HIDDEN; ++hh) s = fmaf(h[hh], w[O2 + o * HIDDEN + hh], s);
      lg[o] = s;
      mx = fmaxf(mx, s);
    }
    float sm = 0.f;
    for (int o = 0; o < OUTC; ++o) sm += __expf(lg[o] - mx);
    const float lse = mx + __logf(sm);
    const int t = tar2[(size_t)b * NTEST + n];
    float lt = lg[0];
    for (int o = 1; o < OUTC; ++o) lt = (o == t) ? lg[o] : lt;
    ce = lse - lt;
  }
  for (int off = 32; off; off >>= 1) ce += __shfl_down(ce, off);
  __shared__ float r[4];
  if ((threadIdx.x & 63) == 0) r[threadIdx.x >> 6] = ce;
  __syncthreads();
  if (threadIdx.x == 0) atomicAdd(accum, r[0] + r[1] + r[2] + r[3]);
}

extern "C" void kernel_launch(void* const* d_in, const int* in_sizes, int n_in,
                              void* d_out, int out_size, void* d_ws, size_t ws_size,
                              hipStream_t stream) {
  const float* inp1   = (const float*)d_in[0];
  const float* tar1   = (const float*)d_in[1];
  const float* inp2   = (const float*)d_in[2];
  const int*   tar2   = (const int*)d_in[3];   // int32 per harness convention
  const float* images = (const float*)d_in[4];
  float*       out    = (float*)d_out;

  const size_t img_bytes  = (size_t)MPAD * KPAD * sizeof(__hip_bfloat16);
  const size_t wall_bytes = (size_t)NCOLS * KPAD * sizeof(__hip_bfloat16);
  const size_t needed     = 256 + img_bytes + wall_bytes;

  if (ws_size >= needed) {
    float* accums = (float*)d_ws;
    __hip_bfloat16* imgb = (__hip_bfloat16*)((char*)d_ws + 256);
    __hip_bfloat16* wall = (__hip_bfloat16*)((char*)d_ws + 256 + img_bytes);
    hipMemsetAsync(d_ws, 0, 256, stream);
    loss1_kernel<<<1024, 256, 0, stream>>>(inp1, tar1, accums);
    cast_prep<<<MPAD + NCOLS, 256, 0, stream>>>(images, inp2, imgb, wall);
    gemm_fused<<<dim3(MTILES, 32), 256, 0, stream>>>(imgb, wall, inp2, tar2, accums);
    finalize<<<1, 1, 0, stream>>>(accums, out);
  } else {
    // fallback: use d_out[1]/d_out[2] as raw accumulators
    hipMemsetAsync(d_out, 0, 3 * sizeof(float), stream);
    loss1_kernel<<<1024, 256, 0, stream>>>(inp1, tar1, out + 1);
    naive_ce<<<(NBATCH * NTEST + 255) / 256, 256, 0, stream>>>(inp2, tar2, images, out + 2);
    finalize<<<1, 1, 0, stream>>>(out + 1, out);
  }
}

// Round 4
// 183.366 us; speedup vs baseline: 1.4864x; 1.2995x over previous
//
#include <hip/hip_runtime.h>
#include <hip/hip_bf16.h>
#include <stdint.h>

// Problem constants
#define INPUT_D 784
#define HIDDEN  64
#define OUTC    10
#define NTEST   10000
#define WVEC    50890
#define NBATCH  64
#define O1      50176      // W1 end / B1 start
#define O2      50240      // W2 start
#define O3      50880      // B2 start
#define KPAD8   896        // 784 padded to 7*128 (fp8 K-tile = 128)
#define MPAD    10240      // 10000 padded to 80*128 (80%8==0 -> row-tile pins to one XCD)
#define MTILES  80
#define NCOLS   4096       // 64 batches * 64 hidden cols
#define KTILES  7
#define H2      136        // hlds row stride (bf16 elements; 272B = 17*16B so b128-aligned)
#define PREP_ROWS (MPAD + NCOLS)
#define L1_BLOCKS 512
#define SCALE1  0x7F7F7F7Fu   // e8m0 127 = 2^0 in all 4 bytes -> scale 1.0

typedef __attribute__((ext_vector_type(8))) short  short8;
typedef __attribute__((ext_vector_type(4))) float  floatx4;
typedef __attribute__((ext_vector_type(4))) int    int4v;
typedef __attribute__((ext_vector_type(8))) int    int8v;

__device__ inline void async_copy16(const void* g, void* lds) {
  __builtin_amdgcn_global_load_lds(
      (const __attribute__((address_space(1))) void*)g,
      (__attribute__((address_space(3))) void*)lds, 16, 0, 0);
}

// ---------------- prep: cast images + W1 to fp8 e4m3 (K-padded) + loss1, one kernel ----
// blocks [0,MPAD): image rows; [MPAD,PREP_ROWS): W1 rows; [PREP_ROWS,+L1_BLOCKS): loss1
__global__ void prep_kernel(const float* __restrict__ img, const float* __restrict__ inp2,
                            const float* __restrict__ l1a, const float* __restrict__ l1b,
                            uint8_t* __restrict__ outI, uint8_t* __restrict__ outW,
                            float* __restrict__ accum) {
  const int blk = blockIdx.x;
  if (blk < PREP_ROWS) {
    const int c = threadIdx.x * 4;           // byte index within padded row
    if (c >= KPAD8) return;
    const float* src;
    uint8_t* dst;
    bool valid;
    if (blk < MPAD) {
      valid = (blk < NTEST);
      src = img + (size_t)blk * INPUT_D;
      dst = outI + (size_t)blk * KPAD8;
    } else {
      const int rr = blk - MPAD;
      valid = true;
      src = inp2 + (size_t)(rr >> 6) * WVEC + (rr & 63) * INPUT_D;
      dst = outW + (size_t)rr * KPAD8;
    }
    float4 v = make_float4(0.f, 0.f, 0.f, 0.f);
    if (valid && (c + 4) <= INPUT_D) v = *(const float4*)(src + c);   // 784%4==0
    uint32_t w = 0;
    w = __builtin_amdgcn_cvt_pk_fp8_f32(v.x, v.y, w, false);  // bytes 0..1
    w = __builtin_amdgcn_cvt_pk_fp8_f32(v.z, v.w, w, true);   // bytes 2..3
    *(uint32_t*)(dst + c) = w;
  } else {
    // loss1: sum of squared diffs
    const int n4 = (NBATCH * WVEC) / 4;   // 814240
    const float4* A4 = (const float4*)l1a;
    const float4* B4 = (const float4*)l1b;
    float s = 0.f;
    for (int i = (blk - PREP_ROWS) * blockDim.x + threadIdx.x; i < n4;
         i += L1_BLOCKS * blockDim.x) {
      float4 x = A4[i], y = B4[i];
      float d0 = x.x - y.x, d1 = x.y - y.y, d2 = x.z - y.z, d3 = x.w - y.w;
      s += d0 * d0 + d1 * d1 + d2 * d2 + d3 * d3;
    }
    for (int off = 32; off; off >>= 1) s += __shfl_down(s, off);
    __shared__ float r[4];
    if ((threadIdx.x & 63) == 0) r[threadIdx.x >> 6] = s;
    __syncthreads();
    if (threadIdx.x == 0) atomicAdd(accum, r[0] + r[1] + r[2] + r[3]);
  }
}

// ---------------- fused GEMM (MX-fp8, scales=1.0) + stage-2 ----------------
// grid (80, 32); block 256. Tile: 128 samples x 128 hcols (2 batches), K-tile 128.
// LDS tiles XOR-swizzled in 16B chunks: phys slot p of row r holds logical chunk p^(r&7).
__global__ __launch_bounds__(256)
void gemm_fused(const uint8_t* __restrict__ A,     // MPAD x KPAD8 fp8
                const uint8_t* __restrict__ Bm,    // NCOLS x KPAD8 fp8
                const float* __restrict__ inp2,
                const int* __restrict__ tar2,      // int32 (harness casts int64->int32)
                float* __restrict__ accums) {
  __shared__ __align__(16) char smem[40032];
  uint8_t* Alds = (uint8_t*)smem;                         // [0,16384): 128 rows x 128B
  uint8_t* Blds = (uint8_t*)(smem + 16384);               // [16384,32768)
  // epilogue overlays
  __hip_bfloat16* hlds  = (__hip_bfloat16*)smem;          // 128*H2*2 = 34816
  __hip_bfloat16* w2lds = (__hip_bfloat16*)(smem + 34816);// 4096 -> 38912
  float*          B2s   = (float*)(smem + 38912);         // 20 floats -> 38992
  int*            tars  = (int*)(smem + 38992);           // 256 ints  -> 40016
  float*          red   = (float*)(smem + 40016);         // 4 floats  -> 40032

  const int tid  = threadIdx.x;
  const int lane = tid & 63;
  const int wave = tid >> 6;
  const int wr   = (wave >> 1) * 64;    // wave row offset in tile
  const int wc   = (wave & 1) * 64;     // wave col offset in tile
  const int row0 = blockIdx.x * 128;
  const int col0 = blockIdx.y * 128;
  const int bbase = col0 >> 6;          // first batch of the 2 this block handles

  floatx4 acc[4][4];
#pragma unroll
  for (int i = 0; i < 4; ++i)
#pragma unroll
    for (int j = 0; j < 4; ++j) acc[i][j] = (floatx4){0.f, 0.f, 0.f, 0.f};

  const int lr   = lane >> 3;                      // row within 8-row chunk
  const int lcB  = (((lane & 7) ^ lr) * 16);       // swizzled source 16B chunk (bytes)
  const int sxor = lane & 7;                       // read-side swizzle (row&7 == lane&7)
  const int q    = lane >> 4;                      // quad
  const int c0   = (2 * q) ^ sxor;                 // phys chunk of logical 2q
  const int c1   = c0 ^ 1;                         // phys chunk of logical 2q+1

  for (int kt = 0; kt < KTILES; ++kt) {
    const int k0 = kt * 128;
#pragma unroll
    for (int c = 0; c < 4; ++c) {
      const int ch = wave * 4 + c;   // 16 chunks of 8 rows each
      async_copy16(A  + (size_t)(row0 + ch * 8 + lr) * KPAD8 + k0 + lcB, Alds + ch * 1024);
      async_copy16(Bm + (size_t)(col0 + ch * 8 + lr) * KPAD8 + k0 + lcB, Blds + ch * 1024);
    }
    __syncthreads();
    int8v a8[4], b8[4];
#pragma unroll
    for (int mi = 0; mi < 4; ++mi) {
      const uint8_t* base = Alds + (wr + mi * 16 + (lane & 15)) * 128;
      int4v lo = *(const int4v*)(base + c0 * 16);
      int4v hi = *(const int4v*)(base + c1 * 16);
      a8[mi] = (int8v){lo.x, lo.y, lo.z, lo.w, hi.x, hi.y, hi.z, hi.w};
    }
#pragma unroll
    for (int ni = 0; ni < 4; ++ni) {
      const uint8_t* base = Blds + (wc + ni * 16 + (lane & 15)) * 128;
      int4v lo = *(const int4v*)(base + c0 * 16);
      int4v hi = *(const int4v*)(base + c1 * 16);
      b8[ni] = (int8v){lo.x, lo.y, lo.z, lo.w, hi.x, hi.y, hi.z, hi.w};
    }
#pragma unroll
    for (int mi = 0; mi < 4; ++mi)
#pragma unroll
      for (int ni = 0; ni < 4; ++ni)
        acc[mi][ni] = __builtin_amdgcn_mfma_scale_f32_16x16x128_f8f6f4(
            a8[mi], b8[ni], acc[mi][ni], 0 /*fp8 A*/, 0 /*fp8 B*/,
            0, SCALE1, 0, SCALE1);
    __syncthreads();
  }

  // ---- epilogue phase 1: load W2(bf16)/B2/targets into LDS; write h(bias+relu, bf16) ----
  for (int i = tid; i < 2048; i += 256) {
    const int bi = i >> 10, rem = i & 1023;
    const int o = rem >> 6, k = rem & 63;
    float v = (o < OUTC) ? inp2[(size_t)(bbase + bi) * WVEC + O2 + o * HIDDEN + k] : 0.f;
    w2lds[i] = __float2bfloat16(v);
  }
  if (tid < 20) B2s[tid] = inp2[(size_t)(bbase + tid / 10) * WVEC + O3 + tid % 10];
  {
    const int bi = tid >> 7, m = tid & 127;
    const int sample = row0 + m;
    tars[tid] = (sample < NTEST) ? tar2[(size_t)(bbase + bi) * NTEST + sample] : 0;
  }
#pragma unroll
  for (int ni = 0; ni < 4; ++ni) {
    const int n = wc + ni * 16 + (lane & 15);  // local col 0..127
    const float b1 = inp2[(size_t)(bbase + (n >> 6)) * WVEC + O1 + (n & 63)];
#pragma unroll
    for (int mi = 0; mi < 4; ++mi) {
      const int m = wr + mi * 16 + q * 4;      // C layout: row=(lane>>4)*4+r, col=lane&15
#pragma unroll
      for (int r = 0; r < 4; ++r) {
        float v = acc[mi][ni][r] + b1;
        hlds[(size_t)(m + r) * H2 + n] = __float2bfloat16(v > 0.f ? v : 0.f);
      }
    }
  }
  __syncthreads();

  // ---- epilogue phase 2: logits via bf16 MFMA, log-softmax via 16-lane shuffles, CE ----
  const int col = lane & 15;
  float celocal = 0.f;
#pragma unroll
  for (int i = 0; i < 4; ++i) {
    const int task = wave * 4 + i;    // 16 tasks: 8 m-tiles x 2 batches
    const int mt = task & 7;
    const int bi = task >> 3;
    short8 af0 = *(const short8*)&hlds[(size_t)(mt * 16 + col) * H2 + bi * 64 + q * 8];
    short8 af1 = *(const short8*)&hlds[(size_t)(mt * 16 + col) * H2 + bi * 64 + 32 + q * 8];
    short8 bf0 = *(const short8*)&w2lds[(bi * 16 + col) * 64 + q * 8];
    short8 bf1 = *(const short8*)&w2lds[(bi * 16 + col) * 64 + 32 + q * 8];
    floatx4 lacc = (floatx4){0.f, 0.f, 0.f, 0.f};
    lacc = __builtin_amdgcn_mfma_f32_16x16x32_bf16(af0, bf0, lacc, 0, 0, 0);
    lacc = __builtin_amdgcn_mfma_f32_16x16x32_bf16(af1, bf1, lacc, 0, 0, 0);
    const float b2 = (col < OUTC) ? B2s[bi * OUTC + col] : 0.f;
#pragma unroll
    for (int r = 0; r < 4; ++r) {
      float lv = (col < OUTC) ? (lacc[r] + b2) : -1e30f;
      float mx = lv;
      mx = fmaxf(mx, __shfl_xor(mx, 1));
      mx = fmaxf(mx, __shfl_xor(mx, 2));
      mx = fmaxf(mx, __shfl_xor(mx, 4));
      mx = fmaxf(mx, __shfl_xor(mx, 8));
      float ex = __expf(lv - mx);
      float sm = ex;
      sm += __shfl_xor(sm, 1);
      sm += __shfl_xor(sm, 2);
      sm += __shfl_xor(sm, 4);
      sm += __shfl_xor(sm, 8);
      const float lse = mx + __logf(sm);
      const int row = mt * 16 + q * 4 + r;
      const int tar = tars[bi * 128 + row];
      if (col == tar && (row0 + row) < NTEST) celocal += (lse - lv);
    }
  }
  for (int off = 32; off; off >>= 1) celocal += __shfl_down(celocal, off);
  if (lane == 0) red[wave] = celocal;
  __syncthreads();
  if (tid == 0) atomicAdd(&accums[1], red[0] + red[1] + red[2] + red[3]);
}

// ---------------- finalize ----------------
__global__ void finalize(const float* __restrict__ accums, float* __restrict__ out) {
  const float l1 = 20.f * accums[0] / (float)(NBATCH * WVEC);
  const float l2 = accums[1] / (float)(NBATCH * NTEST);
  out[0] = l1 + l2;
  out[1] = l1;
  out[2] = l2;
}

// ---------------- fallback (ws too small): naive fp32, correctness only ----------------
__global__ void loss1_fb(const float* __restrict__ a, const float* __restrict__ b,
                         float* __restrict__ accum) {
  const int n4 = (NBATCH * WVEC) / 4;
  const float4* A4 = (const float4*)a;
  const float4* B4 = (const float4*)b;
  float s = 0.f;
  for (int i = blockIdx.x * blockDim.x + threadIdx.x; i < n4; i += gridDim.x * blockDim.x) {
    float4 x = A4[i], y = B4[i];
    float d0 = x.x - y.x, d1 = x.y - y.y, d2 = x.z - y.z, d3 = x.w - y.w;
    s += d0 * d0 + d1 * d1 + d2 * d2 + d3 * d3;
  }
  for (int off = 32; off; off >>= 1) s += __shfl_down(s, off);
  __shared__ float r[4];
  if ((threadIdx.x & 63) == 0) r[threadIdx.x >> 6] = s;
  __syncthreads();
  if (threadIdx.x == 0) atomicAdd(accum, r[0] + r[1] + r[2] + r[3]);
}

__global__ void naive_ce(const float* __restrict__ inp2, const int* __restrict__ tar2,
                         const float* __restrict__ images, float* __restrict__ accum) {
  const int id = blockIdx.x * blockDim.x + threadIdx.x;
  float ce = 0.f;
  if (id < NBATCH * NTEST) {
    const int b = id / NTEST, n = id % NTEST;
    const float* w = inp2 + (size_t)b * WVEC;
    const float* im = images + (size_t)n * INPUT_D;
    float h[HIDDEN];
    for (int hh = 0; hh < HIDDEN; ++hh) {
      float s = w[O1 + hh];
      for (int d = 0; d < INPUT_D; ++d) s = fmaf(im[d], w[hh * INPUT_D + d], s);
      h[hh] = s > 0.f ? s : 0.f;
    }
    float mx = -1e30f, lg[OUTC];
    for (int o = 0; o < OUTC; ++o) {
      float s = w[O3 + o];
      for (int hh = 0; hh < HIDDEN; ++hh) s = fmaf(h[hh], w[O2 + o * HIDDEN + hh], s);
      lg[o] = s;
      mx = fmaxf(mx, s);
    }
    float sm = 0.f;
    for (int o = 0; o < OUTC; ++o) sm += __expf(lg[o] - mx);
    const float lse = mx + __logf(sm);
    const int t = tar2[(size_t)b * NTEST + n];
    float lt = lg[0];
    for (int o = 1; o < OUTC; ++o) lt = (o == t) ? lg[o] : lt;
    ce = lse - lt;
  }
  for (int off = 32; off; off >>= 1) ce += __shfl_down(ce, off);
  __shared__ float r[4];
  if ((threadIdx.x & 63) == 0) r[threadIdx.x >> 6] = ce;
  __syncthreads();
  if (threadIdx.x == 0) atomicAdd(accum, r[0] + r[1] + r[2] + r[3]);
}

extern "C" void kernel_launch(void* const* d_in, const int* in_sizes, int n_in,
                              void* d_out, int out_size, void* d_ws, size_t ws_size,
                              hipStream_t stream) {
  const float* inp1   = (const float*)d_in[0];
  const float* tar1   = (const float*)d_in[1];
  const float* inp2   = (const float*)d_in[2];
  const int*   tar2   = (const int*)d_in[3];   // int32 per harness convention
  const float* images = (const float*)d_in[4];
  float*       out    = (float*)d_out;

  const size_t img_bytes  = (size_t)MPAD * KPAD8;
  const size_t wall_bytes = (size_t)NCOLS * KPAD8;
  const size_t needed     = 256 + img_bytes + wall_bytes;

  if (ws_size >= needed) {
    float* accums = (float*)d_ws;
    uint8_t* imgb = (uint8_t*)d_ws + 256;
    uint8_t* wall = (uint8_t*)d_ws + 256 + img_bytes;
    hipMemsetAsync(d_ws, 0, 256, stream);
    prep_kernel<<<PREP_ROWS + L1_BLOCKS, 256, 0, stream>>>(images, inp2, inp1, tar1,
                                                           imgb, wall, accums);
    gemm_fused<<<dim3(MTILES, 32), 256, 0, stream>>>(imgb, wall, inp2, tar2, accums);
    finalize<<<1, 1, 0, stream>>>(accums, out);
  } else {
    hipMemsetAsync(d_out, 0, 3 * sizeof(float), stream);
    loss1_fb<<<1024, 256, 0, stream>>>(inp1, tar1, out + 1);
    naive_ce<<<(NBATCH * NTEST + 255) / 256, 256, 0, stream>>>(inp2, tar2, images, out + 2);
    finalize<<<1, 1, 0, stream>>>(out + 1, out);
  }
}